// Round 1
// 390.484 us; speedup vs baseline: 1.0149x; 1.0149x over previous
//
#include <hip/hip_runtime.h>

typedef __bf16 bf16x8 __attribute__((ext_vector_type(8)));
typedef __bf16 bf16x4 __attribute__((ext_vector_type(4)));
typedef float f32x4 __attribute__((ext_vector_type(4)));
typedef unsigned short u16;
typedef unsigned long long u64;

#define NX 8388608   // 8192*1024 elements (one [B*T, D] matrix)
#define NW 1048576   // 1024*1024 elements (one weight matrix)

__device__ __forceinline__ u16 f2bf(float f) {
  union { float f; unsigned u; } c; c.f = f;
  unsigned u = c.u;
  u += 0x7fffu + ((u >> 16) & 1u);   // round-to-nearest-even
  return (u16)(u >> 16);
}

__device__ __forceinline__ f32x4 mfma16(bf16x8 a, bf16x8 b, f32x4 c) {
  return __builtin_amdgcn_mfma_f32_16x16x32_bf16(a, b, c, 0, 0, 0);
}

// async global->LDS, 16 B per lane; LDS dest = uniform base + lane*16
__device__ __forceinline__ void gld16(void* lds, const void* g) {
  __builtin_amdgcn_global_load_lds(
      (const __attribute__((address_space(1))) unsigned int*)g,
      (__attribute__((address_space(3))) unsigned int*)lds, 16, 0, 0);
}

// ---------------------------------------------------------------------------
// Kernel 1: cast fp32 -> bf16 for q,k,v and the 4 weight matrices.
// ---------------------------------------------------------------------------
__global__ __launch_bounds__(256) void cast_all(
    const float* __restrict__ q, const float* __restrict__ k,
    const float* __restrict__ v, const float* __restrict__ wq,
    const float* __restrict__ wk, const float* __restrict__ wv,
    const float* __restrict__ wo, u16* __restrict__ xbf, u16* __restrict__ wbf) {
  long long i = ((long long)blockIdx.x * 256 + threadIdx.x) * 8;
  const float* src; u16* dst; long long off;
  if (i < (long long)NX)            { src = q; dst = xbf;            off = i; }
  else if (i < 2LL * NX)            { src = k; dst = xbf + NX;       off = i - NX; }
  else if (i < 3LL * NX)            { src = v; dst = xbf + 2LL * NX; off = i - 2LL * NX; }
  else {
    long long j = i - 3LL * NX;
    int w = (int)(j / NW); off = j - (long long)w * NW;
    src = (w == 0) ? wq : (w == 1) ? wk : (w == 2) ? wv : wo;
    dst = wbf + (long long)w * NW;
  }
  float4 a = *(const float4*)(src + off);
  float4 b = *(const float4*)(src + off + 4);
  u16 o[8] = {f2bf(a.x), f2bf(a.y), f2bf(a.z), f2bf(a.w),
              f2bf(b.x), f2bf(b.y), f2bf(b.z), f2bf(b.w)};
  *(uint4*)(dst + off) = *(const uint4*)o;
}

// ---------------------------------------------------------------------------
// Kernel 1b: pack mask [B,T,T] int32 -> bits [B*T][32] u64 (bit=1: keep).
// ---------------------------------------------------------------------------
__global__ __launch_bounds__(256) void mask_pack(
    const int* __restrict__ mask, u64* __restrict__ bits) {
  const int row = blockIdx.x * 4 + (threadIdx.x >> 6);  // 0..8191
  const int lane = threadIdx.x & 63;
  const int* mrow = mask + (long long)row * 2048;
#pragma unroll
  for (int it = 0; it < 32; it++) {
    u64 w = __ballot(mrow[it * 64 + lane] != 0);
    if (lane == 0) bits[row * 32 + it] = w;
  }
}

// ---------------------------------------------------------------------------
// Kernel 2/4: 128x128x(K=1024) NT-GEMM via global_load_lds + XOR swizzle.
// MODE 0: QKV projection (z selects); Q (pre-scaled by log2e/8), K -> [B,H,T,64];
//         V -> [B,H,64,T] via per-wave LDS transpose (coalesced stores).
// MODE 1: out projection -> fp32 [B*T,1024] + bias.
// ---------------------------------------------------------------------------
template <int MODE>
__global__ __launch_bounds__(256, 2) void gemm128(
    const u16* __restrict__ Abase, const u16* __restrict__ Wbase,
    u16* __restrict__ oq, u16* __restrict__ ok, u16* __restrict__ ovt,
    const float* __restrict__ bias, float* __restrict__ of) {
  __shared__ u16 smem[2][128 * 64];
  u16* sA = smem[0];
  u16* sB = smem[1];
  const u16* A = Abase;
  const u16* W = Wbase;
  if (MODE == 0) { A += (long long)blockIdx.z * NX; W += (long long)blockIdx.z * NW; }
  const int tid = threadIdx.x, wave = tid >> 6, lane = tid & 63;
  const int quad = lane >> 4, l15 = lane & 15;
  const int m0 = blockIdx.y * 128, n0 = blockIdx.x * 128;
  const int wm = (wave & 1) * 64, wn = (wave >> 1) * 64;
  const int lr = lane >> 3;            // 0..7: row within 8-row staging group
  const int gc = (lane & 7) ^ lr;      // global 16B-chunk index for this lane
  f32x4 acc[4][4];
#pragma unroll
  for (int i = 0; i < 4; i++)
#pragma unroll
    for (int j = 0; j < 4; j++) acc[i][j] = (f32x4){0.f, 0.f, 0.f, 0.f};

  for (int ks = 0; ks < 16; ks++) {
    const int k0 = ks * 64;
    __syncthreads();   // previous iteration's frag reads complete
#pragma unroll
    for (int t = 0; t < 4; t++) {
      const int rb = wave * 32 + t * 8;        // wave-uniform row base
      gld16(&sA[rb * 64], &A[(m0 + rb + lr) * 1024 + k0 + gc * 8]);
      gld16(&sB[rb * 64], &W[(n0 + rb + lr) * 1024 + k0 + gc * 8]);
    }
    __syncthreads();   // staging complete (vmcnt drained at barrier)
#pragma unroll
    for (int kc = 0; kc < 2; kc++) {
      bf16x8 aF[4], bF[4];
#pragma unroll
      for (int i = 0; i < 4; i++)
        aF[i] = *(const bf16x8*)&sA[(wm + 16 * i + l15) * 64 +
                                    (((kc * 4 + quad) ^ (l15 & 7)) * 8)];
#pragma unroll
      for (int j = 0; j < 4; j++)
        bF[j] = *(const bf16x8*)&sB[(wn + 16 * j + l15) * 64 +
                                    (((kc * 4 + quad) ^ (l15 & 7)) * 8)];
#pragma unroll
      for (int i = 0; i < 4; i++)
#pragma unroll
        for (int j = 0; j < 4; j++) acc[i][j] = mfma16(aF[i], bF[j], acc[i][j]);
    }
  }

  // Epilogue. C/D layout: row = quad*4 + reg, col = l15 (m89/m91 verified).
  if (MODE == 0) {
    const int z = blockIdx.z;
    if (z < 2) {
      // Q gets the softmax scale log2(e)/8 folded in (pre-bf16-rounding).
      const float qscale = (z == 0) ? 0.18033688f : 1.0f;
      u16* dst = (z == 0) ? oq : ok;
#pragma unroll
      for (int i = 0; i < 4; i++)
#pragma unroll
        for (int j = 0; j < 4; j++)
#pragma unroll
          for (int r = 0; r < 4; r++) {
            int m = m0 + wm + 16 * i + quad * 4 + r;
            int n = n0 + wn + 16 * j + l15;
            int b = m >> 11, t = m & 2047, h = n >> 6, d = n & 63;
            dst[(((b << 4) + h) * 2048 + t) * 64 + d] = f2bf(acc[i][j][r] * qscale);
          }
    } else {
      // V^T: transpose each wave's 64x64 chunk in LDS, store coalesced.
      __syncthreads();                  // all waves done with sA/sB frag reads
      u16* sT = &smem[0][0] + wave * 4096;  // 64x64, chunk-swizzled
#pragma unroll
      for (int i = 0; i < 4; i++)
#pragma unroll
        for (int j = 0; j < 4; j++)
#pragma unroll
          for (int r = 0; r < 4; r++) {
            int m = 16 * i + quad * 4 + r;   // local t (0..63)
            int n = 16 * j + l15;            // local d (0..63)
            sT[n * 64 + (((m >> 3) ^ (n & 7)) * 8) + (m & 7)] = f2bf(acc[i][j][r]);
          }
      // wave-local read-back (in-order DS pipe; no barrier needed)
      const int b = m0 >> 11, t0 = (m0 + wm) & 2047;
      const int h = (n0 + wn) >> 6;   // d-range is 64-aligned
      u16* dst = ovt + ((long long)((b << 4) + h)) * 131072 + lane * 2048 + t0;
#pragma unroll
      for (int c = 0; c < 8; c++) {
        uint4 val = *(const uint4*)&sT[lane * 64 + ((c ^ (lane & 7)) * 8)];
        *(uint4*)(dst + c * 8) = val;
      }
    }
  } else {
    float bb[4];
#pragma unroll
    for (int j = 0; j < 4; j++) bb[j] = bias[n0 + wn + 16 * j + l15];
#pragma unroll
    for (int i = 0; i < 4; i++)
#pragma unroll
      for (int j = 0; j < 4; j++)
#pragma unroll
        for (int r = 0; r < 4; r++) {
          int m = m0 + wm + 16 * i + quad * 4 + r;
          int n = n0 + wn + 16 * j + l15;
          of[m * 1024 + n] = acc[i][j][r] + bb[j];
        }
  }
}

// ---------------------------------------------------------------------------
// Kernel 3: flash attention, v2.
//   - 64-key tiles, double-buffered K/V staging: one barrier per tile, the
//     next tile's global_load_lds issue overlaps the current tile's compute
//     (barrier's implicit vmcnt(0) drain = the only staging sync needed).
//   - LDS 51.2 KB (sK 2x8K + sV 2x8K + sP 18.4K) -> 3 blocks/CU (was 2 @67.6K).
//   - mask all-ones check hoisted to a per-wave prologue; hot loop has no
//     vmem loads besides staging (keeps the vmcnt queue pure).
//   - XCD-bijective block swizzle (1024 = 8*128): each XCD owns 8 whole
//     (b,h) pairs -> K/V working set ~4 MB per XCD L2, no cross-XCD replication.
// K staged key-permuted (kappa(c) = (c&15)*4 + c>>4) so sP is written in
// natural key order as ds_write_b64.
// ---------------------------------------------------------------------------
__device__ __forceinline__ void stage_tile(
    u16* sKb, u16* sVb, const u16* __restrict__ Kh, const u16* __restrict__ Vt,
    int bh, int kt, int wave, int lr8, int gc8) {
#pragma unroll
  for (int t = 0; t < 2; t++) {
    const int rb = wave * 16 + t * 8;          // wave-uniform row base (8 rows/1KB)
    const int c = rb + lr8;                    // LDS row this lane feeds
    const int kap = ((c & 15) << 2) + (c >> 4);  // natural key for perm row c
    gld16(&sKb[rb * 64], &Kh[(bh * 2048 + kt * 64 + kap) * 64 + gc8 * 8]);
    gld16(&sVb[rb * 64], &Vt[(bh * 64 + rb + lr8) * 2048 + kt * 64 + gc8 * 8]);
  }
}

__global__ __launch_bounds__(256, 3) void attn(
    const u16* __restrict__ Qh, const u16* __restrict__ Kh,
    const u16* __restrict__ Vt, const u64* __restrict__ mbits,
    u16* __restrict__ Zc) {
  __shared__ u16 sK[2][64 * 64];               // [perm key c][d], chunk swz ^(c&7)
  __shared__ u16 sV[2][64 * 64];               // [d][key],      chunk swz ^(d&7)
  __shared__ alignas(16) u16 sP[4][32][72];    // per-wave [qrow][key], pad->144B rows
  const int tid = threadIdx.x, wave = tid >> 6, lane = tid & 63;
  const int quad = lane >> 4, l15 = lane & 15;
  // XCD-bijective swizzle: linear id -> (id&7)*128 + id/8; round-robin XCD
  // assignment then gives XCD k the contiguous bh range [8k, 8k+8).
  const int id = blockIdx.y * 16 + blockIdx.x;           // 0..1023
  const int id2 = (id & 7) * 128 + (id >> 3);
  const int bh = id2 >> 4, qt = id2 & 15;
  const int b = bh >> 4, h = bh & 15;
  const int q0 = qt * 128 + wave * 32;
  const int lr8 = lane >> 3, gc8 = (lane & 7) ^ lr8;

  bf16x8 qa[2][2];
#pragma unroll
  for (int g = 0; g < 2; g++)
#pragma unroll
    for (int kc = 0; kc < 2; kc++)
      qa[g][kc] = *(const bf16x8*)&Qh[(bh * 2048 + q0 + g * 16 + l15) * 64 +
                                      kc * 32 + quad * 8];

  // ---- prologue: full-mask check for this wave's 32 rows (all 2048 keys) ----
  const u64* mrow = mbits + (long long)(b * 2048 + q0) * 32;
  u64 am = ~0ull;
#pragma unroll
  for (int i = 0; i < 16; i++) am &= mrow[lane * 16 + i];
  const bool allfull = __all(am == ~0ull);

  const u64* mb[2];
#pragma unroll
  for (int g = 0; g < 2; g++)
    mb[g] = mbits + (long long)(b * 2048 + q0 + g * 16 + quad * 4) * 32;

  f32x4 oacc[2][4];
#pragma unroll
  for (int g = 0; g < 2; g++)
#pragma unroll
    for (int j = 0; j < 4; j++) oacc[g][j] = (f32x4){0.f, 0.f, 0.f, 0.f};
  float lv[2][4] = {{0.f, 0.f, 0.f, 0.f}, {0.f, 0.f, 0.f, 0.f}};

  // prime buffer 0 with tile 0
  stage_tile(&sK[0][0], &sV[0][0], Kh, Vt, bh, 0, wave, lr8, gc8);

  for (int kt = 0; kt < 32; kt++) {
    const int cur = kt & 1;
    __syncthreads();   // tile kt staged (vmcnt drained); buf cur^1 free to refill

    u64 mw[2][4];
    if (!allfull) {    // wave-uniform; issued BEFORE staging so its vmcnt wait
                       // doesn't drain the prefetch queue
#pragma unroll
      for (int g = 0; g < 2; g++)
#pragma unroll
        for (int r = 0; r < 4; r++) mw[g][r] = mb[g][r * 32 + kt];
    }
    if (kt < 31)
      stage_tile(&sK[cur ^ 1][0], &sV[cur ^ 1][0], Kh, Vt, bh, kt + 1,
                 wave, lr8, gc8);   // overlaps with this tile's compute

    // S = Q K^T  (64 permuted columns; kF shared by both row-groups)
    f32x4 sacc[2][4];
#pragma unroll
    for (int g = 0; g < 2; g++)
#pragma unroll
      for (int j = 0; j < 4; j++) sacc[g][j] = (f32x4){0.f, 0.f, 0.f, 0.f};
#pragma unroll
    for (int kc = 0; kc < 2; kc++)
#pragma unroll
      for (int j = 0; j < 4; j++) {
        bf16x8 kF = *(const bf16x8*)&sK[cur][(16 * j + l15) * 64 +
                                            (((kc * 4 + quad) ^ (l15 & 7)) * 8)];
        sacc[0][j] = mfma16(qa[0][kc], kF, sacc[0][j]);
        sacc[1][j] = mfma16(qa[1][kc], kF, sacc[1][j]);
      }

    // p = v_exp(s); masked -> 0. Column (j,l15) = natural key l15*4 + j.
    if (allfull) {
#pragma unroll
      for (int g = 0; g < 2; g++)
#pragma unroll
        for (int r = 0; r < 4; r++) {
          bf16x4 pk;
          float ls = 0.f;
#pragma unroll
          for (int j = 0; j < 4; j++) {
            float p = __builtin_amdgcn_exp2f(sacc[g][j][r]);
            ls += p;
            pk[j] = (__bf16)p;
          }
          lv[g][r] += ls;
          *(bf16x4*)&sP[wave][g * 16 + quad * 4 + r][l15 * 4] = pk;  // wave-local
        }
    } else {
#pragma unroll
      for (int g = 0; g < 2; g++)
#pragma unroll
        for (int r = 0; r < 4; r++) {
          bf16x4 pk;
          float ls = 0.f;
          u64 w = mw[g][r];
#pragma unroll
          for (int j = 0; j < 4; j++) {
            float p = __builtin_amdgcn_exp2f(sacc[g][j][r]);
            p = ((w >> (l15 * 4 + j)) & 1ull) ? p : 0.f;
            ls += p;
            pk[j] = (__bf16)p;
          }
          lv[g][r] += ls;
          *(bf16x4*)&sP[wave][g * 16 + quad * 4 + r][l15 * 4] = pk;
        }
    }

    // O += P V  (natural keys; vF shared by both row-groups)
#pragma unroll
    for (int kc = 0; kc < 2; kc++) {
      bf16x8 aP0 = *(const bf16x8*)&sP[wave][l15][kc * 32 + quad * 8];
      bf16x8 aP1 = *(const bf16x8*)&sP[wave][16 + l15][kc * 32 + quad * 8];
#pragma unroll
      for (int j = 0; j < 4; j++) {
        bf16x8 vF = *(const bf16x8*)&sV[cur][(16 * j + l15) * 64 +
                                            (((kc * 4 + quad) ^ (l15 & 7)) * 8)];
        oacc[0][j] = mfma16(aP0, vF, oacc[0][j]);
        oacc[1][j] = mfma16(aP1, vF, oacc[1][j]);
      }
    }
  }

  // one-time row-sum reduce across the 16 lanes of each quad
#pragma unroll
  for (int g = 0; g < 2; g++) {
    float inv[4];
#pragma unroll
    for (int r = 0; r < 4; r++) {
      float s = lv[g][r];
      s += __shfl_xor(s, 1);
      s += __shfl_xor(s, 2);
      s += __shfl_xor(s, 4);
      s += __shfl_xor(s, 8);
      inv[r] = 1.f / s;
    }
#pragma unroll
    for (int j = 0; j < 4; j++)
#pragma unroll
      for (int r = 0; r < 4; r++) {
        int t = q0 + g * 16 + quad * 4 + r;
        Zc[(b * 2048 + t) * 1024 + h * 64 + 16 * j + l15] =
            f2bf(oacc[g][j][r] * inv[r]);
      }
  }
}

// ---------------------------------------------------------------------------
extern "C" void kernel_launch(void* const* d_in, const int* in_sizes, int n_in,
                              void* d_out, int out_size, void* d_ws, size_t ws_size,
                              hipStream_t stream) {
  (void)in_sizes; (void)n_in; (void)out_size; (void)ws_size;
  const float* q    = (const float*)d_in[0];
  const float* k    = (const float*)d_in[1];
  const float* v    = (const float*)d_in[2];
  const int*   mask = (const int*)d_in[3];
  const float* Wq   = (const float*)d_in[4];
  const float* Wk   = (const float*)d_in[5];
  const float* Wv   = (const float*)d_in[6];
  const float* Wo   = (const float*)d_in[7];
  const float* bo   = (const float*)d_in[8];
  float* out = (float*)d_out;

  u16* Xbf = (u16*)d_ws;             // 3 * NX
  u16* Wbf = Xbf + 3LL * NX;         // 4 * NW
  u16* Qh  = Wbf + 4LL * NW;         // [B,H,T,64]  (pre-scaled by log2e/8)
  u16* Kh  = Qh + (long long)NX;     // [B,H,T,64]
  u16* Vt  = Kh + (long long)NX;     // [B,H,64,T]
  u16* Zc  = Vt + (long long)NX;     // [B*T, 1024]
  u64* Mb  = (u64*)(Zc + (long long)NX);  // [B*T][32] packed mask bits (2 MB)

  cast_all<<<14336, 256, 0, stream>>>(q, k, v, Wq, Wk, Wv, Wo, Xbf, Wbf);
  mask_pack<<<2048, 256, 0, stream>>>(mask, Mb);
  gemm128<0><<<dim3(8, 64, 3), 256, 0, stream>>>(Xbf, Wbf, Qh, Kh, Vt, nullptr, nullptr);
  attn<<<dim3(16, 64), 256, 0, stream>>>(Qh, Kh, Vt, Mb, Zc);
  gemm128<1><<<dim3(8, 64), 256, 0, stream>>>(Zc, Wbf + 3LL * NW, nullptr, nullptr, nullptr,
                                              bo, out);
}